// Round 4
// baseline (462.029 us; speedup 1.0000x reference)
//
#include <hip/hip_runtime.h>

#define NN 50000
#define NE 400000
#define NBATCH 16
#define DH 128
#define DE 64
#define DHID 256
#define EP 72    // Ws LDS row pitch (bf16): 64 + 8
#define SCP 264  // Sc LDS row pitch (bf16): 256 + 8 -> 16B-aligned rows

typedef __attribute__((ext_vector_type(8))) short bf16x8;
typedef __attribute__((ext_vector_type(4))) float f32x4;
typedef __attribute__((ext_vector_type(2))) float f32x2;

__device__ __forceinline__ unsigned f2bf(float x) {
  unsigned u = __float_as_uint(x);
  return (u + 0x7fffu + ((u >> 16) & 1u)) >> 16;
}
__device__ __forceinline__ f32x2 up2(unsigned u) {
  f32x2 r;
  r.x = __uint_as_float(u << 16);
  r.y = __uint_as_float(u & 0xffff0000u);
  return r;
}
__device__ __forceinline__ f32x2 pkadd(f32x2 a, f32x2 b) {
  f32x2 d;
  asm("v_pk_add_f32 %0, %1, %2" : "=v"(d) : "v"(a), "v"(b));
  return d;
}
__device__ __forceinline__ f32x2 pkfma(f32x2 a, f32x2 b, f32x2 c) {
  f32x2 d;
  asm("v_pk_fma_f32 %0, %1, %2, %3" : "=v"(d) : "v"(a), "v"(b), "v"(c));
  return d;
}
__device__ __forceinline__ f32x2 relu2(f32x2 a) {
  f32x2 d;
  d.x = fmaxf(a.x, 0.f);
  d.y = fmaxf(a.y, 0.f);
  return d;
}

// prep: fused {segsum zero, W->bf16 pre-swizzle, Zq GEMV}.
// Blocks 0..575: w2bf + segsum init. Blocks 576..591: Zq (one batch each).
// WbS: 4 sections x 32768 bf16, PRE-SWIZZLED: within section, uint4 slot
// i4 = row*16 + (c16 ^ (row&15)) holds W[koff + c16*8 + comp][row].
// Wbe[256][64]: Wbe[n][k] = W1s[256+k][n].
// Zq permuted fp32: Zq[b*256 + slot], slot = q*64 + t*4 + r, hid = 16t+4q+r.
__global__ void prep(const float* __restrict__ W1g, const float* __restrict__ W1s,
                     const float* __restrict__ qm, const float* __restrict__ b1g,
                     unsigned short* __restrict__ WbS, unsigned short* __restrict__ Wbe,
                     float* __restrict__ Zq, float* __restrict__ segsum) {
  int bx = blockIdx.x;
  if (bx < 576) {
    int idx = bx * 256 + threadIdx.x;   // 147456 total
    if (idx < NN) segsum[idx] = 0.0f;
    if (idx < 131072) {
      int sec = idx >> 15, el = idx & 32767;
      int i4 = el >> 3, comp = el & 7;
      int row = i4 >> 4, swz = i4 & 15;
      int c16 = swz ^ (row & 15);
      int k = c16 * 8 + comp;
      const float* W = (sec & 1) ? W1s : W1g;
      int koff = (sec >> 1) * 128;
      WbS[idx] = (unsigned short)f2bf(W[(koff + k) * DHID + row]);
    } else {
      int i = idx - 131072;
      int n = i >> 6, k = i & 63;
      Wbe[i] = (unsigned short)f2bf(W1s[(2 * DH + k) * DHID + n]);
    }
  } else {
    int b = bx - 576, c = threadIdx.x;
    float acc = b1g[c];
#pragma unroll 4
    for (int k = 0; k < DH; ++k)
      acc = fmaf(qm[b * DH + k], W1g[(2 * DH + k) * DHID + c], acc);
    int t = c >> 4, qq = (c >> 2) & 3, r = c & 3;
    Zq[b * 256 + qq * 64 + t * 4 + r] = acc;
  }
}

// Node projections: block = 128 nodes x 2 sections (looped), K=128.
// Bs (h tile, 32KB) staged ONCE per block and reused by both sections
// (halves staging work + h traffic vs one-section blocks). A fragments read
// straight from the pre-swizzled, L2-resident WbS. Grid (391,2) = 782 blocks
// -> ~3 blocks/CU resident, good tail balance.
// P: per node 1024 bf16 = 4 sections x 256 slots; slot = q*64 + t*4 + r.
__global__ __launch_bounds__(256, 4)
void node_gemm(const float* __restrict__ h, const unsigned short* __restrict__ WbS,
               unsigned short* __restrict__ P) {
  __shared__ unsigned short Bs[128 * 128];  // 32KB
  const int tid = threadIdx.x;
  const int lane = tid & 63, wave = tid >> 6;
  const int node0 = blockIdx.x * 128;
  const int secbase = blockIdx.y * 2;

#pragma unroll
  for (int it = 0; it < 16; ++it) {   // stage B: 4096 float4 = 128 rows x 32
    int fi = it * 256 + tid;
    int row = fi >> 5, f4 = fi & 31;
    int n = node0 + row;
    float4 v = make_float4(0.f, 0.f, 0.f, 0.f);
    if (n < NN) v = *(const float4*)&h[(size_t)n * DH + f4 * 4];
    uint2 pk = make_uint2(f2bf(v.x) | (f2bf(v.y) << 16),
                          f2bf(v.z) | (f2bf(v.w) << 16));
    int ch = f4 >> 1, half = f4 & 1;
    *(uint2*)(Bs + row * 128 + ((ch ^ (row & 15)) * 8 + half * 4)) = pk;
  }
  __syncthreads();

  const int r15 = lane & 15, q = lane >> 4;
  for (int sp = 0; sp < 2; ++sp) {
    const int sec = secbase + sp;
    const unsigned short* Wsec = WbS + (size_t)sec * 32768;
#pragma unroll
    for (int hf = 0; hf < 2; ++hf) {
      f32x4 acc[4][4];
#pragma unroll
      for (int mi = 0; mi < 4; ++mi)
#pragma unroll
        for (int nj = 0; nj < 4; ++nj) acc[mi][nj] = (f32x4)(0.f);

#pragma unroll
      for (int ki = 0; ki < 4; ++ki) {
        const int c16 = ki * 4 + q;
        bf16x8 bfr[4];
#pragma unroll
        for (int nj = 0; nj < 4; ++nj)
          bfr[nj] = *(const bf16x8*)(Bs + (hf * 64 + nj * 16 + r15) * 128 + ((c16 ^ r15) * 8));
#pragma unroll
        for (int mi = 0; mi < 4; ++mi) {
          int hr = wave * 64 + mi * 16 + r15;        // hr & 15 == r15
          bf16x8 a = *(const bf16x8*)(Wsec + (hr * 16 + (c16 ^ r15)) * 8);
#pragma unroll
          for (int nj = 0; nj < 4; ++nj)
            acc[mi][nj] = __builtin_amdgcn_mfma_f32_16x16x32_bf16(a, bfr[nj], acc[mi][nj], 0, 0, 0);
        }
      }
      // paired writeback: t=wave*4+mp*2 and t+1 are contiguous 8B -> uint4
#pragma unroll
      for (int mp = 0; mp < 2; ++mp) {
        int t = wave * 4 + mp * 2;
#pragma unroll
        for (int nj = 0; nj < 4; ++nj) {
          int node = node0 + hf * 64 + nj * 16 + r15;
          if (node < NN) {
            f32x4 v0 = acc[mp * 2][nj], v1 = acc[mp * 2 + 1][nj];
            uint4 pk;
            pk.x = f2bf(v0.x) | (f2bf(v0.y) << 16);
            pk.y = f2bf(v0.z) | (f2bf(v0.w) << 16);
            pk.z = f2bf(v1.x) | (f2bf(v1.y) << 16);
            pk.w = f2bf(v1.z) | (f2bf(v1.w) << 16);
            *(uint4*)(P + (size_t)node * 1024 + sec * 256 + q * 64 + t * 4) = pk;
          }
        }
      }
    }
  }
}

// Fused edge kernel: MFMA e-GEMM (b1s folded into acc init; e loaded per-lane,
// converted in-register) -> Sc via LDS round-trip (aliases Ws) -> packed-f32
// gather epilogue -> exp + segsum atomicAdd (max-free softmax: |raw| <= ~4,
// exp(raw) cannot overflow; math identical to the max-subtracted form).
// LDS = 40704B (+pad -> 40960) => 4 blocks/CU.
__global__ __launch_bounds__(256, 4)
void edge_kernel(const float* __restrict__ eattr, const int* __restrict__ eidx,
                 const int* __restrict__ ebat, const unsigned short* __restrict__ Wbe,
                 const float* __restrict__ b1s,
                 const float* __restrict__ W2g, const float* __restrict__ b2g,
                 const float* __restrict__ W2s, const float* __restrict__ b2s,
                 const unsigned short* __restrict__ P, const float* __restrict__ Zq,
                 float* __restrict__ out, float* __restrict__ segsum) {
  __shared__ unsigned short Ws[256 * EP];   // 36864B; aliased as Sc after GEMM
  __shared__ float w2g_s[256], w2s_s[256], b1s_s[256];  // slot-permuted
  __shared__ int src_s[64], dst_s[64], bat_s[64];
  const int tid = threadIdx.x;
  const int lane = tid & 63, wave = tid >> 6;
  const int e0 = blockIdx.x * 64;

  {
    const uint4* srcw = (const uint4*)Wbe;   // 2048 uint4
#pragma unroll
    for (int it = 0; it < 8; ++it) {
      int i = it * 256 + tid;
      int row = i >> 3, c8 = i & 7;
      *(uint4*)(Ws + row * EP + c8 * 8) = srcw[i];
    }
  }
  {
    int c = tid;                           // slot -> hid = 16t + 4q + r
    int qq = c >> 6, t = (c >> 2) & 15, r = c & 3;
    int hid = t * 16 + qq * 4 + r;
    w2g_s[c] = W2g[hid];
    w2s_s[c] = W2s[hid];
    b1s_s[c] = b1s[hid];
  }
  if (tid < 64) {
    src_s[tid] = eidx[e0 + tid];
    dst_s[tid] = eidx[NE + e0 + tid];
    bat_s[tid] = ebat[e0 + tid];
  }
  __syncthreads();

  const int r15 = lane & 15, q = lane >> 4;
  const int cx = lane & 31, eh = lane >> 5;
  const int eloc = wave * 16 + r15;
  const uint4* Pq = (const uint4*)P;   // node row = 128 uint4

  // round-0 gather prefetch: L3 latency hides under the GEMM
  int er = wave * 16 + eh;
  int s = src_s[er], d = dst_s[er], b = bat_s[er];
  uint4 gi_n = Pq[(size_t)s * 128 + cx];
  uint4 ss_n = Pq[(size_t)s * 128 + 32 + cx];
  uint4 gj_n = Pq[(size_t)d * 128 + 64 + cx];
  uint4 sd_n = Pq[(size_t)d * 128 + 96 + cx];

  // per-lane e load + in-register bf16 convert (rows contiguous -> coalesced).
  // Element j of eb0 = e[e0+eloc][q*8+j]; eb1 = cols 32+q*8+j (same as the
  // old staged-es layout).
  const float* erow = eattr + (size_t)(e0 + eloc) * DE;
  float4 ea0 = *(const float4*)&erow[q * 8];
  float4 ea1 = *(const float4*)&erow[q * 8 + 4];
  float4 ec0 = *(const float4*)&erow[32 + q * 8];
  float4 ec1 = *(const float4*)&erow[32 + q * 8 + 4];
  uint4 u0, u1;
  u0.x = f2bf(ea0.x) | (f2bf(ea0.y) << 16);
  u0.y = f2bf(ea0.z) | (f2bf(ea0.w) << 16);
  u0.z = f2bf(ea1.x) | (f2bf(ea1.y) << 16);
  u0.w = f2bf(ea1.z) | (f2bf(ea1.w) << 16);
  u1.x = f2bf(ec0.x) | (f2bf(ec0.y) << 16);
  u1.y = f2bf(ec0.z) | (f2bf(ec0.w) << 16);
  u1.z = f2bf(ec1.x) | (f2bf(ec1.y) << 16);
  u1.w = f2bf(ec1.z) | (f2bf(ec1.w) << 16);
  bf16x8 eb0 = __builtin_bit_cast(bf16x8, u0);
  bf16x8 eb1 = __builtin_bit_cast(bf16x8, u1);

  f32x4 acc[16];
#pragma unroll
  for (int t = 0; t < 16; ++t)           // b1s folded into accumulator init
    acc[t] = *(const f32x4*)&b1s_s[q * 64 + t * 4];
#pragma unroll
  for (int t = 0; t < 16; ++t) {
    bf16x8 a0 = *(const bf16x8*)(Ws + (t * 16 + r15) * EP + q * 8);
    bf16x8 a1 = *(const bf16x8*)(Ws + (t * 16 + r15) * EP + 32 + q * 8);
    acc[t] = __builtin_amdgcn_mfma_f32_16x16x32_bf16(a0, eb0, acc[t], 0, 0, 0);
    acc[t] = __builtin_amdgcn_mfma_f32_16x16x32_bf16(a1, eb1, acc[t], 0, 0, 0);
  }

  __syncthreads();                 // all Ws reads done; safe to alias
  unsigned short* Sc = Ws;         // [64][SCP] bf16, slot order
#pragma unroll
  for (int t2 = 0; t2 < 8; ++t2) {  // paired: two f32x4 -> one uint4 store
    f32x4 v0 = acc[2 * t2], v1 = acc[2 * t2 + 1];
    uint4 pk;
    pk.x = f2bf(v0.x) | (f2bf(v0.y) << 16);
    pk.y = f2bf(v0.z) | (f2bf(v0.w) << 16);
    pk.z = f2bf(v1.x) | (f2bf(v1.y) << 16);
    pk.w = f2bf(v1.z) | (f2bf(v1.w) << 16);
    *(uint4*)(Sc + eloc * SCP + q * 64 + t2 * 8) = pk;
  }
  __syncthreads();

  // ---- packed-f32 gather epilogue: 2 edges/wave/round, 8 rounds ----
  const float b2gv = b2g[0], b2sv = b2s[0];
  const int so = cx * 8;
  const f32x2* wgp = (const f32x2*)&w2g_s[so];
  const f32x2* wsp = (const f32x2*)&w2s_s[so];
  f32x2 wg2[4] = {wgp[0], wgp[1], wgp[2], wgp[3]};
  f32x2 ws2[4] = {wsp[0], wsp[1], wsp[2], wsp[3]};

  for (int rr = 0; rr < 8; ++rr) {
    uint4 gi = gi_n, ssv = ss_n, gj = gj_n, sdv = sd_n;
    const int ercur = er, dcur = d, bcur = b;
    if (rr < 7) {
      er = wave * 16 + (rr + 1) * 2 + eh;
      s = src_s[er]; d = dst_s[er]; b = bat_s[er];
      gi_n = Pq[(size_t)s * 128 + cx];
      ss_n = Pq[(size_t)s * 128 + 32 + cx];
      gj_n = Pq[(size_t)d * 128 + 64 + cx];
      sd_n = Pq[(size_t)d * 128 + 96 + cx];
    }
    uint4 sc = *(const uint4*)(Sc + ercur * SCP + so);
    float4 z0 = *(const float4*)&Zq[bcur * 256 + so];
    float4 z1 = *(const float4*)&Zq[bcur * 256 + so + 4];
    f32x2 zq2[4];
    zq2[0].x = z0.x; zq2[0].y = z0.y; zq2[1].x = z0.z; zq2[1].y = z0.w;
    zq2[2].x = z1.x; zq2[2].y = z1.y; zq2[3].x = z1.z; zq2[3].y = z1.w;
    const unsigned gia[4] = {gi.x, gi.y, gi.z, gi.w};
    const unsigned gja[4] = {gj.x, gj.y, gj.z, gj.w};
    const unsigned sca[4] = {sc.x, sc.y, sc.z, sc.w};
    const unsigned ssa[4] = {ssv.x, ssv.y, ssv.z, ssv.w};
    const unsigned sda[4] = {sdv.x, sdv.y, sdv.z, sdv.w};
    f32x2 gp2 = (f32x2)(0.f), sp2 = (f32x2)(0.f);
#pragma unroll
    for (int i = 0; i < 4; ++i) {
      f32x2 g = pkadd(pkadd(up2(gia[i]), up2(gja[i])), zq2[i]);
      gp2 = pkfma(relu2(g), wg2[i], gp2);
      f32x2 sv = pkadd(pkadd(up2(sca[i]), up2(ssa[i])), up2(sda[i]));
      sp2 = pkfma(relu2(sv), ws2[i], sp2);
    }
    float gp = gp2.x + gp2.y, sp = sp2.x + sp2.y;
#pragma unroll
    for (int m = 16; m >= 1; m >>= 1) {   // reduce within 32-lane half
      gp += __shfl_xor(gp, m);
      sp += __shfl_xor(sp, m);
    }
    if (cx == 0) {
      float gate = 1.f / (1.f + __expf(-(gp + b2gv)));
      float ex = __expf(gate * (sp + b2sv));   // max-free softmax numerator
      out[e0 + ercur] = ex;
      atomicAdd(&segsum[dcur], ex);
    }
  }
}

__global__ void norm_pass(float* __restrict__ out, const int* __restrict__ dstp,
                          const float* __restrict__ segsum) {
  int i = blockIdx.x * 256 + threadIdx.x;
  if (i < NE) out[i] = out[i] / fmaxf(segsum[dstp[i]], 1e-9f);
}

extern "C" void kernel_launch(void* const* d_in, const int* in_sizes, int n_in,
                              void* d_out, int out_size, void* d_ws, size_t ws_size,
                              hipStream_t stream) {
  const float* h   = (const float*)d_in[0];
  const float* e   = (const float*)d_in[1];
  const float* q   = (const float*)d_in[2];
  const int* eidx  = (const int*)d_in[3];
  const int* ebat  = (const int*)d_in[4];
  const float* W1g = (const float*)d_in[5];
  const float* b1g = (const float*)d_in[6];
  const float* W2g = (const float*)d_in[7];
  const float* b2g = (const float*)d_in[8];
  const float* W1s = (const float*)d_in[9];
  const float* b1s = (const float*)d_in[10];
  const float* W2s = (const float*)d_in[11];
  const float* b2s = (const float*)d_in[12];
  float* out = (float*)d_out;

  // ws carve: P(bf16 102.4MB) | Zq(16KB) | segsum | WbS | Wbe
  unsigned short* P = (unsigned short*)d_ws;
  float* Zq = (float*)(P + (size_t)NN * 1024);
  float* segsum = Zq + NBATCH * DHID;
  unsigned short* WbS = (unsigned short*)(segsum + NN);
  unsigned short* Wbe = WbS + 131072;

  hipLaunchKernelGGL(prep, dim3(592), dim3(256), 0, stream,
                     W1g, W1s, q, b1g, WbS, Wbe, Zq, segsum);
  hipLaunchKernelGGL(node_gemm, dim3(391, 2), dim3(256), 0, stream, h, WbS, P);
  hipLaunchKernelGGL(edge_kernel, dim3(NE / 64), dim3(256), 0, stream,
                     e, eidx, ebat, Wbe, b1s, W2g, b2g, W2s, b2s, P, Zq, out, segsum);
  hipLaunchKernelGGL(norm_pass, dim3(1563), dim3(256), 0, stream,
                     out, eidx + NE, segsum);
}

// Round 5
// 358.205 us; speedup vs baseline: 1.2898x; 1.2898x over previous
//
#include <hip/hip_runtime.h>

#define NN 50000
#define NE 400000
#define NBATCH 16
#define DH 128
#define DE 64
#define DHID 256
#define EP 72    // Ws LDS row pitch (bf16): 64 + 8
#define SCP 264  // Sc LDS row pitch (bf16): 256 + 8 -> 16B-aligned rows

typedef __attribute__((ext_vector_type(8))) short bf16x8;
typedef __attribute__((ext_vector_type(4))) float f32x4;
typedef __attribute__((ext_vector_type(2))) float f32x2;

// Slot map (involution, swaps hid bit-fields [5:4]<->[3:2]):
// hid = 16t + 4q + r  <->  slot = (t>>2)*64 + q*16 + (t&3)*4 + r.
// perm(x) works both directions (slot->hid and hid->slot).
__device__ __forceinline__ int perm(int c) {
  return (c & 0xC3) | ((c & 0x0C) << 2) | ((c & 0x30) >> 2);
}

__device__ __forceinline__ unsigned f2bf(float x) {
  unsigned u = __float_as_uint(x);
  return (u + 0x7fffu + ((u >> 16) & 1u)) >> 16;
}
__device__ __forceinline__ f32x2 up2(unsigned u) {
  f32x2 r;
  r.x = __uint_as_float(u << 16);
  r.y = __uint_as_float(u & 0xffff0000u);
  return r;
}
__device__ __forceinline__ f32x2 pkadd(f32x2 a, f32x2 b) {
  f32x2 d;
  asm("v_pk_add_f32 %0, %1, %2" : "=v"(d) : "v"(a), "v"(b));
  return d;
}
__device__ __forceinline__ f32x2 pkfma(f32x2 a, f32x2 b, f32x2 c) {
  f32x2 d;
  asm("v_pk_fma_f32 %0, %1, %2, %3" : "=v"(d) : "v"(a), "v"(b), "v"(c));
  return d;
}
__device__ __forceinline__ f32x2 relu2(f32x2 a) {
  f32x2 d;
  d.x = fmaxf(a.x, 0.f);
  d.y = fmaxf(a.y, 0.f);
  return d;
}

// prep: fused {segsum zero, W->bf16 pre-swizzle, Zq GEMV}.
// Blocks 0..575: w2bf + segsum init. Blocks 576..591: Zq (one batch each).
// WbS: 4 sections x 32768 bf16, PRE-SWIZZLED: within section, uint4 slot
// i4 = row*16 + (c16 ^ (row&15)) holds W[koff + c16*8 + comp][row].
// Wbe[256][64]: Wbe[n][k] = W1s[256+k][n].
// Zq permuted fp32: Zq[b*256 + slot], slot = perm(hid).
__global__ void prep(const float* __restrict__ W1g, const float* __restrict__ W1s,
                     const float* __restrict__ qm, const float* __restrict__ b1g,
                     unsigned short* __restrict__ WbS, unsigned short* __restrict__ Wbe,
                     float* __restrict__ Zq, float* __restrict__ segsum) {
  int bx = blockIdx.x;
  if (bx < 576) {
    int idx = bx * 256 + threadIdx.x;   // 147456 total
    if (idx < NN) segsum[idx] = 0.0f;
    if (idx < 131072) {
      int sec = idx >> 15, el = idx & 32767;
      int i4 = el >> 3, comp = el & 7;
      int row = i4 >> 4, swz = i4 & 15;
      int c16 = swz ^ (row & 15);
      int k = c16 * 8 + comp;
      const float* W = (sec & 1) ? W1s : W1g;
      int koff = (sec >> 1) * 128;
      WbS[idx] = (unsigned short)f2bf(W[(koff + k) * DHID + row]);
    } else {
      int i = idx - 131072;
      int n = i >> 6, k = i & 63;
      Wbe[i] = (unsigned short)f2bf(W1s[(2 * DH + k) * DHID + n]);
    }
  } else {
    int b = bx - 576, c = threadIdx.x;   // c = hid
    float acc = b1g[c];
#pragma unroll 4
    for (int k = 0; k < DH; ++k)
      acc = fmaf(qm[b * DH + k], W1g[(2 * DH + k) * DHID + c], acc);
    Zq[b * 256 + perm(c)] = acc;
  }
}

// Node projections: block = 128 nodes x 1 section (256 hid), K=128.
// Bs (h tile, 32KB) is the ONLY LDS; A fragments read straight from the
// pre-swizzled, L2-resident WbS. Grid (391,4) -> 1564 blocks, 4 blocks/CU.
// P: per node 1024 bf16 = 4 sections x 256 slots; slot = perm(hid) so each
// wave owns a contiguous 128B region per node -> full-line HBM writes
// (fixes the 3.3x WRITE_SIZE amplification + RMW fetch seen in round 4).
__global__ __launch_bounds__(256, 4)
void node_gemm(const float* __restrict__ h, const unsigned short* __restrict__ WbS,
               unsigned short* __restrict__ P) {
  __shared__ unsigned short Bs[128 * 128];  // 32KB
  const int tid = threadIdx.x;
  const int lane = tid & 63, wave = tid >> 6;
  const int node0 = blockIdx.x * 128;
  const int sec = blockIdx.y;
  const unsigned short* Wsec = WbS + (size_t)sec * 32768;

#pragma unroll
  for (int it = 0; it < 16; ++it) {   // stage B: 4096 float4 = 128 rows x 32
    int fi = it * 256 + tid;
    int row = fi >> 5, f4 = fi & 31;
    int n = node0 + row;
    float4 v = make_float4(0.f, 0.f, 0.f, 0.f);
    if (n < NN) v = *(const float4*)&h[(size_t)n * DH + f4 * 4];
    uint2 pk = make_uint2(f2bf(v.x) | (f2bf(v.y) << 16),
                          f2bf(v.z) | (f2bf(v.w) << 16));
    int ch = f4 >> 1, half = f4 & 1;
    *(uint2*)(Bs + row * 128 + ((ch ^ (row & 15)) * 8 + half * 4)) = pk;
  }
  __syncthreads();

  const int r15 = lane & 15, q = lane >> 4;
#pragma unroll
  for (int hf = 0; hf < 2; ++hf) {
    f32x4 acc[4][4];
#pragma unroll
    for (int mi = 0; mi < 4; ++mi)
#pragma unroll
      for (int nj = 0; nj < 4; ++nj) acc[mi][nj] = (f32x4)(0.f);

#pragma unroll
    for (int ki = 0; ki < 4; ++ki) {
      const int c16 = ki * 4 + q;
      bf16x8 bfr[4];
#pragma unroll
      for (int nj = 0; nj < 4; ++nj)
        bfr[nj] = *(const bf16x8*)(Bs + (hf * 64 + nj * 16 + r15) * 128 + ((c16 ^ r15) * 8));
#pragma unroll
      for (int mi = 0; mi < 4; ++mi) {
        int hr = wave * 64 + mi * 16 + r15;        // hr & 15 == r15
        bf16x8 a = *(const bf16x8*)(Wsec + (hr * 16 + (c16 ^ r15)) * 8);
#pragma unroll
        for (int nj = 0; nj < 4; ++nj)
          acc[mi][nj] = __builtin_amdgcn_mfma_f32_16x16x32_bf16(a, bfr[nj], acc[mi][nj], 0, 0, 0);
      }
    }
    // writeback: lane owns slots [wave*64 + q*16, +16) per node -> 2 uint4
    // stores back-to-back (32B contiguous); the q-neighbor lanes of the SAME
    // wave complete each 64B line within the same instruction pair.
#pragma unroll
    for (int nj = 0; nj < 4; ++nj) {
      int node = node0 + hf * 64 + nj * 16 + r15;
      if (node < NN) {
        unsigned short* pp = P + (size_t)node * 1024 + sec * 256 + wave * 64 + q * 16;
#pragma unroll
        for (int mp = 0; mp < 2; ++mp) {
          f32x4 v0 = acc[mp * 2][nj], v1 = acc[mp * 2 + 1][nj];
          uint4 pk;
          pk.x = f2bf(v0.x) | (f2bf(v0.y) << 16);
          pk.y = f2bf(v0.z) | (f2bf(v0.w) << 16);
          pk.z = f2bf(v1.x) | (f2bf(v1.y) << 16);
          pk.w = f2bf(v1.z) | (f2bf(v1.w) << 16);
          *(uint4*)(pp + mp * 8) = pk;
        }
      }
    }
  }
}

// Fused edge kernel: MFMA e-GEMM (b1s folded into acc init; e loaded per-lane,
// converted in-register) -> Sc via LDS round-trip (aliases Ws) -> packed-f32
// gather epilogue -> exp + segsum atomicAdd (max-free softmax: |raw| <= ~4,
// exp(raw) cannot overflow; math identical to the max-subtracted form).
// LDS = 40704B (+pad -> 40960) => 4 blocks/CU.
__global__ __launch_bounds__(256, 4)
void edge_kernel(const float* __restrict__ eattr, const int* __restrict__ eidx,
                 const int* __restrict__ ebat, const unsigned short* __restrict__ Wbe,
                 const float* __restrict__ b1s,
                 const float* __restrict__ W2g, const float* __restrict__ b2g,
                 const float* __restrict__ W2s, const float* __restrict__ b2s,
                 const unsigned short* __restrict__ P, const float* __restrict__ Zq,
                 float* __restrict__ out, float* __restrict__ segsum) {
  __shared__ unsigned short Ws[256 * EP];   // 36864B; aliased as Sc after GEMM
  __shared__ float w2g_s[256], w2s_s[256], b1s_s[256];  // slot-permuted
  __shared__ int src_s[64], dst_s[64], bat_s[64];
  const int tid = threadIdx.x;
  const int lane = tid & 63, wave = tid >> 6;
  const int e0 = blockIdx.x * 64;

  {
    const uint4* srcw = (const uint4*)Wbe;   // 2048 uint4
#pragma unroll
    for (int it = 0; it < 8; ++it) {
      int i = it * 256 + tid;
      int row = i >> 3, c8 = i & 7;
      *(uint4*)(Ws + row * EP + c8 * 8) = srcw[i];
    }
  }
  {
    int c = tid;                           // c = slot; hid = perm(slot)
    int hid = perm(c);
    w2g_s[c] = W2g[hid];
    w2s_s[c] = W2s[hid];
    b1s_s[c] = b1s[hid];
  }
  if (tid < 64) {
    src_s[tid] = eidx[e0 + tid];
    dst_s[tid] = eidx[NE + e0 + tid];
    bat_s[tid] = ebat[e0 + tid];
  }
  __syncthreads();

  const int r15 = lane & 15, q = lane >> 4;
  const int cx = lane & 31, eh = lane >> 5;
  const int eloc = wave * 16 + r15;
  const uint4* Pq = (const uint4*)P;   // node row = 128 uint4

  // round-0 gather prefetch: L3 latency hides under the GEMM
  int er = wave * 16 + eh;
  int s = src_s[er], d = dst_s[er], b = bat_s[er];
  uint4 gi_n = Pq[(size_t)s * 128 + cx];
  uint4 ss_n = Pq[(size_t)s * 128 + 32 + cx];
  uint4 gj_n = Pq[(size_t)d * 128 + 64 + cx];
  uint4 sd_n = Pq[(size_t)d * 128 + 96 + cx];

  // per-lane e load + in-register bf16 convert (rows contiguous -> coalesced).
  const float* erow = eattr + (size_t)(e0 + eloc) * DE;
  float4 ea0 = *(const float4*)&erow[q * 8];
  float4 ea1 = *(const float4*)&erow[q * 8 + 4];
  float4 ec0 = *(const float4*)&erow[32 + q * 8];
  float4 ec1 = *(const float4*)&erow[32 + q * 8 + 4];
  uint4 u0, u1;
  u0.x = f2bf(ea0.x) | (f2bf(ea0.y) << 16);
  u0.y = f2bf(ea0.z) | (f2bf(ea0.w) << 16);
  u0.z = f2bf(ea1.x) | (f2bf(ea1.y) << 16);
  u0.w = f2bf(ea1.z) | (f2bf(ea1.w) << 16);
  u1.x = f2bf(ec0.x) | (f2bf(ec0.y) << 16);
  u1.y = f2bf(ec0.z) | (f2bf(ec0.w) << 16);
  u1.z = f2bf(ec1.x) | (f2bf(ec1.y) << 16);
  u1.w = f2bf(ec1.z) | (f2bf(ec1.w) << 16);
  bf16x8 eb0 = __builtin_bit_cast(bf16x8, u0);
  bf16x8 eb1 = __builtin_bit_cast(bf16x8, u1);

  f32x4 acc[16];
#pragma unroll
  for (int t = 0; t < 16; ++t)   // b1s folded in; slot = (t>>2)*64+q*16+(t&3)*4
    acc[t] = *(const f32x4*)&b1s_s[(t >> 2) * 64 + q * 16 + (t & 3) * 4];
#pragma unroll
  for (int t = 0; t < 16; ++t) {
    bf16x8 a0 = *(const bf16x8*)(Ws + (t * 16 + r15) * EP + q * 8);
    bf16x8 a1 = *(const bf16x8*)(Ws + (t * 16 + r15) * EP + 32 + q * 8);
    acc[t] = __builtin_amdgcn_mfma_f32_16x16x32_bf16(a0, eb0, acc[t], 0, 0, 0);
    acc[t] = __builtin_amdgcn_mfma_f32_16x16x32_bf16(a1, eb1, acc[t], 0, 0, 0);
  }

  __syncthreads();                 // all Ws reads done; safe to alias
  unsigned short* Sc = Ws;         // [64][SCP] bf16, slot order
#pragma unroll
  for (int t2 = 0; t2 < 8; ++t2) {  // slots (t2>>1)*64 + q*16 + (t2&1)*8 .. +7
    f32x4 v0 = acc[2 * t2], v1 = acc[2 * t2 + 1];
    uint4 pk;
    pk.x = f2bf(v0.x) | (f2bf(v0.y) << 16);
    pk.y = f2bf(v0.z) | (f2bf(v0.w) << 16);
    pk.z = f2bf(v1.x) | (f2bf(v1.y) << 16);
    pk.w = f2bf(v1.z) | (f2bf(v1.w) << 16);
    *(uint4*)(Sc + eloc * SCP + (t2 >> 1) * 64 + q * 16 + (t2 & 1) * 8) = pk;
  }
  __syncthreads();

  // ---- packed-f32 gather epilogue: 2 edges/wave/round, 8 rounds ----
  const float b2gv = b2g[0], b2sv = b2s[0];
  const int so = cx * 8;
  const f32x2* wgp = (const f32x2*)&w2g_s[so];
  const f32x2* wsp = (const f32x2*)&w2s_s[so];
  f32x2 wg2[4] = {wgp[0], wgp[1], wgp[2], wgp[3]};
  f32x2 ws2[4] = {wsp[0], wsp[1], wsp[2], wsp[3]};

  for (int rr = 0; rr < 8; ++rr) {
    uint4 gi = gi_n, ssv = ss_n, gj = gj_n, sdv = sd_n;
    const int ercur = er, dcur = d, bcur = b;
    if (rr < 7) {
      er = wave * 16 + (rr + 1) * 2 + eh;
      s = src_s[er]; d = dst_s[er]; b = bat_s[er];
      gi_n = Pq[(size_t)s * 128 + cx];
      ss_n = Pq[(size_t)s * 128 + 32 + cx];
      gj_n = Pq[(size_t)d * 128 + 64 + cx];
      sd_n = Pq[(size_t)d * 128 + 96 + cx];
    }
    uint4 sc = *(const uint4*)(Sc + ercur * SCP + so);
    float4 z0 = *(const float4*)&Zq[bcur * 256 + so];
    float4 z1 = *(const float4*)&Zq[bcur * 256 + so + 4];
    f32x2 zq2[4];
    zq2[0].x = z0.x; zq2[0].y = z0.y; zq2[1].x = z0.z; zq2[1].y = z0.w;
    zq2[2].x = z1.x; zq2[2].y = z1.y; zq2[3].x = z1.z; zq2[3].y = z1.w;
    const unsigned gia[4] = {gi.x, gi.y, gi.z, gi.w};
    const unsigned gja[4] = {gj.x, gj.y, gj.z, gj.w};
    const unsigned sca[4] = {sc.x, sc.y, sc.z, sc.w};
    const unsigned ssa[4] = {ssv.x, ssv.y, ssv.z, ssv.w};
    const unsigned sda[4] = {sdv.x, sdv.y, sdv.z, sdv.w};
    f32x2 gp2 = (f32x2)(0.f), sp2 = (f32x2)(0.f);
#pragma unroll
    for (int i = 0; i < 4; ++i) {
      f32x2 g = pkadd(pkadd(up2(gia[i]), up2(gja[i])), zq2[i]);
      gp2 = pkfma(relu2(g), wg2[i], gp2);
      f32x2 sv = pkadd(pkadd(up2(sca[i]), up2(ssa[i])), up2(sda[i]));
      sp2 = pkfma(relu2(sv), ws2[i], sp2);
    }
    float gp = gp2.x + gp2.y, sp = sp2.x + sp2.y;
#pragma unroll
    for (int m = 16; m >= 1; m >>= 1) {   // reduce within 32-lane half
      gp += __shfl_xor(gp, m);
      sp += __shfl_xor(sp, m);
    }
    if (cx == 0) {
      float gate = 1.f / (1.f + __expf(-(gp + b2gv)));
      float ex = __expf(gate * (sp + b2sv));   // max-free softmax numerator
      out[e0 + ercur] = ex;
      atomicAdd(&segsum[dcur], ex);
    }
  }
}

__global__ void norm_pass(float* __restrict__ out, const int* __restrict__ dstp,
                          const float* __restrict__ segsum) {
  int i = blockIdx.x * 256 + threadIdx.x;
  if (i < NE) out[i] = out[i] / fmaxf(segsum[dstp[i]], 1e-9f);
}

extern "C" void kernel_launch(void* const* d_in, const int* in_sizes, int n_in,
                              void* d_out, int out_size, void* d_ws, size_t ws_size,
                              hipStream_t stream) {
  const float* h   = (const float*)d_in[0];
  const float* e   = (const float*)d_in[1];
  const float* q   = (const float*)d_in[2];
  const int* eidx  = (const int*)d_in[3];
  const int* ebat  = (const int*)d_in[4];
  const float* W1g = (const float*)d_in[5];
  const float* b1g = (const float*)d_in[6];
  const float* W2g = (const float*)d_in[7];
  const float* b2g = (const float*)d_in[8];
  const float* W1s = (const float*)d_in[9];
  const float* b1s = (const float*)d_in[10];
  const float* W2s = (const float*)d_in[11];
  const float* b2s = (const float*)d_in[12];
  float* out = (float*)d_out;

  // ws carve: P(bf16 102.4MB) | Zq(16KB) | segsum | WbS | Wbe
  unsigned short* P = (unsigned short*)d_ws;
  float* Zq = (float*)(P + (size_t)NN * 1024);
  float* segsum = Zq + NBATCH * DHID;
  unsigned short* WbS = (unsigned short*)(segsum + NN);
  unsigned short* Wbe = WbS + 131072;

  hipLaunchKernelGGL(prep, dim3(592), dim3(256), 0, stream,
                     W1g, W1s, q, b1g, WbS, Wbe, Zq, segsum);
  hipLaunchKernelGGL(node_gemm, dim3(391, 4), dim3(256), 0, stream, h, WbS, P);
  hipLaunchKernelGGL(edge_kernel, dim3(NE / 64), dim3(256), 0, stream,
                     e, eidx, ebat, Wbe, b1s, W2g, b2g, W2s, b2s, P, Zq, out, segsum);
  hipLaunchKernelGGL(norm_pass, dim3(1563), dim3(256), 0, stream,
                     out, eidx + NE, segsum);
}